// Round 15
// baseline (321.399 us; speedup 1.0000x reference)
//
#include <hip/hip_runtime.h>
#include <math.h>

#define S_  2048
#define B_  2
#define M_  512
#define H_  12
#define D_  64
#define DM_ 768
#define K_  2560

typedef short bf16x8 __attribute__((ext_vector_type(8)));
typedef float f32x4  __attribute__((ext_vector_type(4)));
typedef unsigned short u16;
typedef unsigned short u16x4 __attribute__((ext_vector_type(4)));
typedef unsigned short u16x8 __attribute__((ext_vector_type(8)));
typedef unsigned long long u64;

// score prescale: 0.125 * log2(e)  (softmax done in exp2 domain)
#define CSC 0.18033688011112042f

static __device__ __forceinline__ u16 f2bf(float f) {
    unsigned u = __float_as_uint(f);
    u += 0x7fffu + ((u >> 16) & 1u);
    return (u16)(u >> 16);
}
static __device__ __forceinline__ u16 f2bf_fast(float f) {   // round-half-up, 2 ops
    return (u16)((__float_as_uint(f) + 0x8000u) >> 16);
}
static __device__ __forceinline__ float bf2f(u16 h) {
    return __uint_as_float(((unsigned)h) << 16);
}
static __device__ __forceinline__ float exp2_fast(float x) {
    float r;
    asm("v_exp_f32 %0, %1" : "=v"(r) : "v"(x));
    return r;
}
static __device__ __forceinline__ unsigned cvt_pk_bf16(float lo, float hi) {
    unsigned r;
    asm("v_cvt_pk_bf16_f32 %0, %1, %2" : "=v"(r) : "v"(lo), "v"(hi));
    return r;
}
static __device__ __forceinline__ void gll16(const u16* g, u16* l) {
    __builtin_amdgcn_global_load_lds(
        (const __attribute__((address_space(1))) unsigned int*)g,
        (__attribute__((address_space(3))) unsigned int*)l, 16, 0, 0);
}
// LDS drain + barrier WITHOUT vmcnt drain (keeps prefetch loads in flight)
static __device__ __forceinline__ void lgkm_barrier() {
    asm volatile("s_waitcnt lgkmcnt(0)" ::: "memory");
    __builtin_amdgcn_s_barrier();
}
#define MFMA16(a,b,c) __builtin_amdgcn_mfma_f32_16x16x32_bf16((a),(b),(c),0,0,0)

// ---------------------------------------------------------------------------
// cast fp32 -> bf16, 8 segments + mask bitpack (z=8) in one launch
// ---------------------------------------------------------------------------
struct Cast8 {
    const float* src[8];
    u16*         dst[8];
    int          n4[8];
};
__global__ __launch_bounds__(256)
void castk(Cast8 c, const int* __restrict__ am, u64* __restrict__ mb)
{
    const int seg = blockIdx.y;
    if (seg == 8) {   // mask bitpack, grid-stride (wave-aligned: N,stride %64==0)
        const size_t N = (size_t)B_ * S_ * S_;
        for (size_t idx = (size_t)blockIdx.x * 256 + threadIdx.x; idx < N;
             idx += (size_t)3072 * 256) {
            const int v = am[idx];
            const u64 bal = __ballot(v != 0);
            if ((threadIdx.x & 63) == 0) mb[idx >> 6] = bal;
        }
        return;
    }
    const int i = blockIdx.x * 256 + threadIdx.x;
    if (i >= c.n4[seg]) return;
    const float4 v = *(const float4*)(c.src[seg] + (size_t)i * 4);
    u16x4 o;
    o[0] = f2bf(v.x); o[1] = f2bf(v.y); o[2] = f2bf(v.z); o[3] = f2bf(v.w);
    *(u16x4*)(c.dst[seg] + (size_t)i * 4) = o;
}

// ---------------------------------------------------------------------------
// FUSED bf16 MFMA projection GEMMs — one launch, mode = blockIdx.z.
// BK=64 staging (12 K-steps; 32 MFMA/step/wave).  (unchanged)
// ---------------------------------------------------------------------------
struct GFused {
    const u16*   W[4];
    const u16*   A[4];
    const float* bias[4];
    const float* uvec;
    const float* vvec;
    u16*         out0[4];
    u16*         out1;       // qv (mode 0 only)
    int          ny[4];
};
__global__ __launch_bounds__(256)
void gemm_fused(GFused g)
{
    const int mode = blockIdx.z;
    if ((int)blockIdx.y >= g.ny[mode]) return;

    __shared__ __align__(16) u16 Wt[128 * 64];
    __shared__ __align__(16) u16 At[128 * 64];

    const int tid = threadIdx.x;
    const int w = tid >> 6, lane = tid & 63;
    const int l15 = lane & 15, lq = lane >> 4;
    const int wm = w >> 1, wn = w & 1;
    const int c0 = blockIdx.x * 128, r0 = blockIdx.y * 128;

    const u16* __restrict__ Wb = g.W[mode];
    const u16* __restrict__ Ab = g.A[mode];
    const float* __restrict__ bias = g.bias[mode];

    f32x4 acc[4][4];
    #pragma unroll
    for (int mi = 0; mi < 4; ++mi)
        #pragma unroll
        for (int ni = 0; ni < 4; ++ni) acc[mi][ni] = (f32x4){0.f, 0.f, 0.f, 0.f};

    for (int k0 = 0; k0 < DM_; k0 += 64) {
        __syncthreads();
        #pragma unroll
        for (int q = 0; q < 4; ++q) {
            const int inst = w * 4 + q;
            const int sl = inst * 64 + lane;
            const int row = sl >> 3, cp = sl & 7, ch = cp ^ (row & 7);
            gll16(Wb + (size_t)(c0 + row) * DM_ + k0 + ch * 8, Wt + inst * 512);
            gll16(Ab + (size_t)(r0 + row) * DM_ + k0 + ch * 8, At + inst * 512);
        }
        __syncthreads();
        #pragma unroll
        for (int h2 = 0; h2 < 2; ++h2) {
            const int s8 = lq + h2 * 4;
            bf16x8 wf[4], af[4];
            #pragma unroll
            for (int mi = 0; mi < 4; ++mi) {
                const int row = wm * 64 + mi * 16 + l15;
                wf[mi] = *(const bf16x8*)&Wt[row * 64 + (s8 ^ (row & 7)) * 8];
            }
            #pragma unroll
            for (int ni = 0; ni < 4; ++ni) {
                const int row = wn * 64 + ni * 16 + l15;
                af[ni] = *(const bf16x8*)&At[row * 64 + (s8 ^ (row & 7)) * 8];
            }
            #pragma unroll
            for (int mi = 0; mi < 4; ++mi)
                #pragma unroll
                for (int ni = 0; ni < 4; ++ni)
                    acc[mi][ni] = MFMA16(wf[mi], af[ni], acc[mi][ni]);
        }
    }

    if (mode == 0) {
        #pragma unroll
        for (int mi = 0; mi < 4; ++mi) {
            const int cb = c0 + wm * 64 + mi * 16 + lq * 4;
            const float4 bb = *(const float4*)(bias + cb);
            const float4 uu = *(const float4*)(g.uvec + cb);
            const float4 vv = *(const float4*)(g.vvec + cb);
            const int qh = cb >> 6, qd = cb & 63;
            #pragma unroll
            for (int ni = 0; ni < 4; ++ni) {
                const int r = r0 + wn * 64 + ni * 16 + l15;
                const f32x4 a = acc[mi][ni];
                const float v0 = a[0] + bb.x, v1 = a[1] + bb.y;
                const float v2 = a[2] + bb.z, v3 = a[3] + bb.w;
                const int s = r >> 1, b = r & 1;
                const size_t off = ((size_t)(b * H_ + qh) * S_ + s) * D_ + qd;
                u16x4 o1, o2;
                o1[0] = f2bf((v0 + uu.x) * CSC); o1[1] = f2bf((v1 + uu.y) * CSC);
                o1[2] = f2bf((v2 + uu.z) * CSC); o1[3] = f2bf((v3 + uu.w) * CSC);
                o2[0] = f2bf((v0 + vv.x) * CSC); o2[1] = f2bf((v1 + vv.y) * CSC);
                o2[2] = f2bf((v2 + vv.z) * CSC); o2[3] = f2bf((v3 + vv.w) * CSC);
                *(u16x4*)(g.out0[0] + off) = o1;
                *(u16x4*)(g.out1 + off) = o2;
            }
        }
    } else if (mode == 1) {
        #pragma unroll
        for (int mi = 0; mi < 4; ++mi) {
            const int cb = c0 + wm * 64 + mi * 16 + lq * 4;
            const float4 bb = *(const float4*)(bias + cb);
            const int qh = cb >> 6, qd = cb & 63;
            #pragma unroll
            for (int ni = 0; ni < 4; ++ni) {
                const int r = r0 + wn * 64 + ni * 16 + l15;
                const f32x4 a = acc[mi][ni];
                int j, b;
                if (r < M_ * B_) { j = r >> 1; b = r & 1; }
                else { const int rr = r - M_ * B_; j = M_ + (rr >> 1); b = rr & 1; }
                const size_t off = ((size_t)(b * H_ + qh) * K_ + j) * D_ + qd;
                u16x4 o1;
                o1[0] = f2bf(a[0] + bb.x); o1[1] = f2bf(a[1] + bb.y);
                o1[2] = f2bf(a[2] + bb.z); o1[3] = f2bf(a[3] + bb.w);
                *(u16x4*)(g.out0[1] + off) = o1;
            }
        }
    } else if (mode == 2) {
        #pragma unroll
        for (int mi = 0; mi < 4; ++mi) {
            const int cb = c0 + wm * 64 + mi * 16 + lq * 4;
            const float4 bb = *(const float4*)(bias + cb);
            const int qh = cb >> 6, qd = cb & 63;
            #pragma unroll
            for (int ni = 0; ni < 4; ++ni) {
                const int r = r0 + wn * 64 + ni * 16 + l15;
                const f32x4 a = acc[mi][ni];
                int j, b;
                if (r < M_ * B_) { j = r >> 1; b = r & 1; }
                else { const int rr = r - M_ * B_; j = M_ + (rr >> 1); b = rr & 1; }
                const size_t rowb = ((size_t)(b * H_ + qh) * 64 + qd);
                u16* o = g.out0[2];
                o[(rowb + 0) * K_ + j] = f2bf(a[0] + bb.x);
                o[(rowb + 1) * K_ + j] = f2bf(a[1] + bb.y);
                o[(rowb + 2) * K_ + j] = f2bf(a[2] + bb.z);
                o[(rowb + 3) * K_ + j] = f2bf(a[3] + bb.w);
            }
        }
    } else {
        #pragma unroll
        for (int mi = 0; mi < 4; ++mi) {
            const int cb = c0 + wm * 64 + mi * 16 + lq * 4;
            const float4 bb = *(const float4*)(bias + cb);
            const int qh = cb >> 6, qd = cb & 63;
            #pragma unroll
            for (int ni = 0; ni < 4; ++ni) {
                const int r = r0 + wn * 64 + ni * 16 + l15;
                const f32x4 a = acc[mi][ni];
                const size_t off = ((size_t)qh * K_ + r) * D_ + qd;
                u16x4 o1;
                o1[0] = f2bf(a[0] + bb.x); o1[1] = f2bf(a[1] + bb.y);
                o1[2] = f2bf(a[2] + bb.z); o1[3] = f2bf(a[3] + bb.w);
                *(u16x4*)(g.out0[3] + off) = o1;
            }
        }
    }
}

// ---------------------------------------------------------------------------
// O-projection GEMM with FUSED 4-way split-K combine (reg-staged)
// ---------------------------------------------------------------------------
__global__ __launch_bounds__(256)
void gemm_oproj(const u16* __restrict__ Wb, const u16* __restrict__ pO,
                const float* __restrict__ pm, const float* __restrict__ pl,
                const float* __restrict__ bias, float* __restrict__ out)
{
    __shared__ __align__(16) u16 Wt[128 * 32];
    __shared__ __align__(16) u16 At[128 * 32];

    const int tid = threadIdx.x;
    const int w = tid >> 6, lane = tid & 63;
    const int l15 = lane & 15, lq = lane >> 4;
    const int wm = w >> 1, wn = w & 1;
    const int c0 = blockIdx.x * 128, r0 = blockIdx.y * 128;

    int rowq[2], cpq[2];
    #pragma unroll
    for (int q = 0; q < 2; ++q) {
        const int sl = (w * 2 + q) * 64 + lane;
        rowq[q] = sl >> 2; cpq[q] = sl & 3;
    }

    bf16x8 wreg[2], pr[2][4];
    float  mr[2][4], lr[2][4];

    auto LOADSTAGE = [&](int k0) {
        #pragma unroll
        for (int q = 0; q < 2; ++q) {
            const int row = rowq[q], cp = cpq[q];
            const int c8 = k0 + cp * 8;
            wreg[q] = *(const bf16x8*)(Wb + (size_t)(c0 + row) * DM_ + c8);
            const int tr = r0 + row;
            const int b = tr >> 11, s = tr & 2047;
            const int h = c8 >> 6, d0 = c8 & 63;
            const int unit = (b * H_ + h) * 16 + (s >> 7);
            const int rt = s & 127;
            const size_t u4 = (size_t)unit * 4;
            #pragma unroll
            for (int i = 0; i < 4; ++i) {
                mr[q][i] = pm[(u4 + i) * 128 + rt];
                lr[q][i] = pl[(u4 + i) * 128 + rt];
                pr[q][i] = *(const bf16x8*)(pO + (u4 + i) * 8192 + rt * 64 + d0);
            }
        }
    };
    auto WRITESTAGE = [&]() {
        #pragma unroll
        for (int q = 0; q < 2; ++q) {
            const int row = rowq[q], cp = cpq[q];
            const int j8 = (cp ^ (row & 3)) * 8;
            *(bf16x8*)&Wt[row * 32 + j8] = wreg[q];
            const float M = fmaxf(fmaxf(mr[q][0], mr[q][1]),
                                  fmaxf(mr[q][2], mr[q][3]));
            float wgt[4], den = 0.f;
            #pragma unroll
            for (int i = 0; i < 4; ++i) {
                wgt[i] = exp2_fast(mr[q][i] - M);
                den += wgt[i] * lr[q][i];
            }
            const float inv = 1.f / den;
            #pragma unroll
            for (int i = 0; i < 4; ++i) wgt[i] *= inv;
            u16x8 o;
            #pragma unroll
            for (int e = 0; e < 8; ++e) {
                float v = wgt[0] * bf2f((u16)pr[q][0][e]);
                v += wgt[1] * bf2f((u16)pr[q][1][e]);
                v += wgt[2] * bf2f((u16)pr[q][2][e]);
                v += wgt[3] * bf2f((u16)pr[q][3][e]);
                o[e] = f2bf(v);
            }
            *(u16x8*)&At[row * 32 + j8] = o;
        }
    };

    f32x4 acc[4][4];
    #pragma unroll
    for (int mi = 0; mi < 4; ++mi)
        #pragma unroll
        for (int ni = 0; ni < 4; ++ni) acc[mi][ni] = (f32x4){0.f, 0.f, 0.f, 0.f};

    LOADSTAGE(0);
    for (int k0 = 0; k0 < DM_; k0 += 32) {
        __syncthreads();
        WRITESTAGE();
        if (k0 + 32 < DM_) LOADSTAGE(k0 + 32);
        lgkm_barrier();
        bf16x8 wf[4], af[4];
        #pragma unroll
        for (int mi = 0; mi < 4; ++mi) {
            const int row = wm * 64 + mi * 16 + l15;
            wf[mi] = *(const bf16x8*)&Wt[row * 32 + (lq ^ (row & 3)) * 8];
        }
        #pragma unroll
        for (int ni = 0; ni < 4; ++ni) {
            const int row = wn * 64 + ni * 16 + l15;
            af[ni] = *(const bf16x8*)&At[row * 32 + (lq ^ (row & 3)) * 8];
        }
        __builtin_amdgcn_s_setprio(1);
        #pragma unroll
        for (int mi = 0; mi < 4; ++mi)
            #pragma unroll
            for (int ni = 0; ni < 4; ++ni)
                acc[mi][ni] = MFMA16(wf[mi], af[ni], acc[mi][ni]);
        __builtin_amdgcn_s_setprio(0);
    }

    #pragma unroll
    for (int mi = 0; mi < 4; ++mi) {
        const int cb = c0 + wm * 64 + mi * 16 + lq * 4;
        const float4 bb = *(const float4*)(bias + cb);
        #pragma unroll
        for (int ni = 0; ni < 4; ++ni) {
            const int r = r0 + wn * 64 + ni * 16 + l15;
            const f32x4 a = acc[mi][ni];
            float4 val;
            val.x = a[0] + bb.x; val.y = a[1] + bb.y;
            val.z = a[2] + bb.z; val.w = a[3] + bb.w;
            *(float4*)(out + (size_t)r * DM_ + cb) = val;
        }
    }
}

// ---------------------------------------------------------------------------
// bf16 MFMA flash attention — 8-wave / 128-q-row blocks, 4-way split-K.
// LDS: kt single-buffer (8KB) + vt 3-slot (24KB) + band 192-row circular
// (24KB) + sc 128x72 (18KB) = 76.5KB -> exactly 2 blocks/CU, 16 waves/CU.
// kt(t+1) + 64 new band rows are prefetched AFTER a mid-tile lgkm_barrier
// (kt/band retired); V(t+1) at tile top. Per-wave inner code identical to
// the proven 4-wave version (cgo = 7-w; wrap row is ql=127 / qv[i0+128]).
// ---------------------------------------------------------------------------
template<int MODE>
static __device__ __forceinline__ void attn_tile_step(
    const int t, const int i0, const int tid, const int tlo, const int thi,
    const u16* __restrict__ kbb, const u16* __restrict__ vbb,
    const u16* __restrict__ krb, const u64* __restrict__ mrow64,
    const bf16x8 (&quA)[2], const bf16x8 (&qvA)[2],
    u16* kt, u16* bandc, u16* vtbuf, u16* sc, float* r128s,
    const float* qv128f,
    f32x4 (&oacc)[4], float& m_run, float& l_run)
{
    const int w = tid >> 6, lane = tid & 63;
    const int l15 = lane & 15, lq = lane >> 4;
    const int ql = w * 16 + l15;               // this lane's softmax row
    const int j0 = t * 64;
    const int diff_base = j0 - i0 - 127;
    const int base = (t % 3) * 64;             // circular band window base
    const int cgo = 7 - w;                     // BD cg offset for this wave
    u16* vtP = vtbuf + ((t + 2) % 3) * 4096;   // V(t-1) slot
    const bool last = (t == thi - 1);

    __syncthreads();   // publish kt(t)/band(t)/vt(t); drains gll

    // --- V(t+1) prefetch (slot disjoint from vtP and vt(t)) ---
    if (!last) {
        const int j0n = j0 + 64;
        u16* vtN = vtbuf + ((t + 1) % 3) * 4096;
        const int d = w * 8 + (lane >> 3);
        const int c = (lane & 7) ^ (d & 7);
        gll16(vbb + (size_t)d * K_ + j0n + c * 8, vtN + w * 512);
    }

    // --- mask word for this lane's row (1 load) ---
    const u64 mw = (j0 >= M_) ? mrow64[(size_t)ql * 32 + ((j0 - M_) >> 6)] : ~0ull;

    // --- MFMA cluster: AC^T(t) [swapped], BD(t) [pruned], PV(t-1) ---
    f32x4 ac[4];
    #pragma unroll
    for (int cg = 0; cg < 4; ++cg) ac[cg] = (f32x4){0.f, 0.f, 0.f, 0.f};
    f32x4 bd[5];
    #pragma unroll
    for (int cgi = 0; cgi < 5; ++cgi) bd[cgi] = (f32x4){0.f, 0.f, 0.f, 0.f};
    __builtin_amdgcn_s_setprio(1);
    #pragma unroll
    for (int h2 = 0; h2 < 2; ++h2) {
        const int d0 = lq * 8 + h2 * 32;
        #pragma unroll
        for (int cg = 0; cg < 4; ++cg) {
            const int key = cg * 16 + l15;
            const bf16x8 aK = *(const bf16x8*)&kt[key * 64 + (d0 ^ ((key & 7) << 3))];
            ac[cg] = MFMA16(aK, quA[h2], ac[cg]);   // SWAPPED: C = S^T
        }
        #pragma unroll
        for (int cgi = 0; cgi < 5; ++cgi) {
            const int dd = (cgi + cgo) * 16 + l15;
            int prow = base + dd; if (prow >= 192) prow -= 192;
            const bf16x8 bB = *(const bf16x8*)&bandc[prow * 64 + (d0 ^ ((prow & 7) << 3))];
            bd[cgi] = MFMA16(qvA[h2], bB, bd[cgi]);
        }
    }
    if (t > tlo) {   // PV(t-1): P from sc (A-frag layout), V^T from vtP
        #pragma unroll
        for (int kh = 0; kh < 2; ++kh) {
            const int key0 = lq * 8 + kh * 32;
            const bf16x8 pA = *(const bf16x8*)&sc[ql * 72 + kh * 32 + lq * 8];
            #pragma unroll
            for (int cg = 0; cg < 4; ++cg) {
                const int d = cg * 16 + l15;
                const bf16x8 vB = *(const bf16x8*)&vtP[d * 64 + (key0 ^ ((d & 7) << 3))];
                oacc[cg] = MFMA16(pA, vB, oacc[cg]);
            }
        }
    }
    __builtin_amdgcn_s_setprio(0);

    // --- BD row 128 (wrap source), keys 0..63, reads bandc ---
    float rv = 0.f;
    const int rdd = tid >> 1;
    if (MODE != 0 && tid < 128) {
        const int half = tid & 1;
        int prow = base + rdd; if (prow >= 192) prow -= 192;
        #pragma unroll
        for (int c2 = 0; c2 < 4; ++c2) {
            const int d0 = half * 32 + c2 * 8;
            const bf16x8 bv = *(const bf16x8*)&bandc[prow * 64 + (d0 ^ ((prow & 7) << 3))];
            #pragma unroll
            for (int e = 0; e < 8; ++e)
                rv = fmaf(bf2f((u16)bv[e]), qv128f[d0 + e], rv);
        }
        rv += __shfl_xor(rv, 1, 64);
    }

    lgkm_barrier();   // all waves done reading kt/band (+ PV's sc reads)

    // --- kt(t+1) + 64 new band rows into retired space ---
    if (!last) {
        const int j0n = j0 + 64;
        {
            const int key = w * 8 + (lane >> 3);
            const int chunk = (lane & 7) ^ (key & 7);
            gll16(kbb + (size_t)(j0n + key) * 64 + chunk * 8, kt + w * 512);
        }
        {
            const int rl = w * 8 + (lane >> 3);
            const int prow = base + rl;                      // retired rows
            const int diff = (j0 - i0 + 65) + rl;
            const int rrow = (diff <= 512) ? (diff + 2047)
                           : ((diff == 513) ? 0 : (diff - 514));
            const int chunk = (lane & 7) ^ (prow & 7);
            gll16(krb + (size_t)rrow * 64 + chunk * 8, bandc + (base + w * 8) * 64);
        }
    }

    // --- scatter BD -> sc (bf16, stride 72) ---
    const int e0 = l15 + lq * 4 - 15;
    if (MODE == 0) {
        #pragma unroll
        for (int r = 0; r < 4; ++r) {
            const int e = e0 + r;
            u16* rowp = sc + (w * 16 + lq * 4 + r) * 72;
            rowp[e & 63]  = (e < 0) ? f2bf_fast(bd[4][r]) : f2bf_fast(bd[0][r]);
            rowp[16 + e] = f2bf_fast(bd[1][r]);
            rowp[32 + e] = f2bf_fast(bd[2][r]);
            rowp[48 + e] = f2bf_fast(bd[3][r]);
        }
    } else if (MODE == 1) {
        #pragma unroll
        for (int r = 0; r < 4; ++r) {
            const int e1 = e0 + r - 1;
            const int rowm = w * 16 + lq * 4 + r - 1;
            if (rowm >= 0) {
                u16* rowp = sc + rowm * 72;
                rowp[e1 & 63] = (e1 < 0) ? f2bf_fast(bd[4][r]) : f2bf_fast(bd[0][r]);
                rowp[16 + e1] = f2bf_fast(bd[1][r]);
                rowp[32 + e1] = f2bf_fast(bd[2][r]);
                rowp[48 + e1] = f2bf_fast(bd[3][r]);
            }
        }
    } else {   // MODE 2: mixed regimes, predicated (<=3 tiles per block)
        #pragma unroll
        for (int cgi = 0; cgi < 5; ++cgi) {
            const int dd = (cgi + cgo) * 16 + l15;
            const int diff_e = diff_base + dd;
            #pragma unroll
            for (int r = 0; r < 4; ++r) {
                const int qlb = w * 16 + lq * 4 + r;
                const int key_n = dd + qlb - 127;
                const u16 val = f2bf_fast(bd[cgi][r]);
                if (diff_e <= 512) {
                    if ((unsigned)key_n < 64u) sc[qlb * 72 + key_n] = val;
                } else if (diff_e >= 514) {
                    const int key_w = key_n - 1;
                    if ((unsigned)key_w < 64u && qlb >= 1) sc[(qlb - 1) * 72 + key_w] = val;
                }
            }
        }
    }
    if (MODE != 0 && tid < 128 && (tid & 1) == 0) r128s[rdd] = rv;

    if (MODE != 0) lgkm_barrier();   // cross-wave sc rows + r128s visible

    // --- softmax (per-lane row ql), exp2 domain, deferred max ---
    float s[4][4];
    #pragma unroll
    for (int cg = 0; cg < 4; ++cg) {
        const u16x4 bq = *(const u16x4*)&sc[ql * 72 + cg * 16 + lq * 4];
        #pragma unroll
        for (int r = 0; r < 4; ++r) {
            const int key = cg * 16 + lq * 4 + r;
            float bdv = bf2f(bq[r]);
            if (MODE == 1) {
                if (ql == 127) bdv = r128s[key];
            } else if (MODE == 2) {
                const int diff = (j0 - i0) + key - ql;
                if (diff == 513) bdv = 0.f;
                else if (diff >= 514 && ql == 127) bdv = r128s[key];
            }
            s[cg][r] = ac[cg][r] + bdv;
        }
    }
    if (mw != ~0ull) {   // mask fast-path: never taken for all-ones mask
        #pragma unroll
        for (int cg = 0; cg < 4; ++cg)
            #pragma unroll
            for (int r = 0; r < 4; ++r) {
                const int key = cg * 16 + lq * 4 + r;
                if (!((mw >> key) & 1ull)) s[cg][r] = -3.0e8f;
            }
    }
    float mcg[4];
    #pragma unroll
    for (int cg = 0; cg < 4; ++cg)
        mcg[cg] = fmaxf(fmaxf(s[cg][0], s[cg][1]), fmaxf(s[cg][2], s[cg][3]));
    float mx = fmaxf(fmaxf(mcg[0], mcg[1]), fmaxf(mcg[2], mcg[3]));
    mx = fmaxf(mx, __shfl_xor(mx, 16, 64));
    mx = fmaxf(mx, __shfl_xor(mx, 32, 64));
    if (!__all(mx <= m_run)) {       // exact deferred-max update (rare)
        const float mn = fmaxf(m_run, mx);
        const float fr = exp2_fast(m_run - mn);
        m_run = mn;
        l_run *= fr;
        #pragma unroll
        for (int r = 0; r < 4; ++r) {
            const float fb = __shfl(fr, lq * 4 + r, 64);
            #pragma unroll
            for (int cg = 0; cg < 4; ++cg) oacc[cg][r] *= fb;
        }
    }
    float ltc[4];
    #pragma unroll
    for (int cg = 0; cg < 4; ++cg) {
        const float p0 = exp2_fast(s[cg][0] - m_run);
        const float p1 = exp2_fast(s[cg][1] - m_run);
        const float p2 = exp2_fast(s[cg][2] - m_run);
        const float p3 = exp2_fast(s[cg][3] - m_run);
        ltc[cg] = (p0 + p1) + (p2 + p3);
        uint2 pk;
        pk.x = cvt_pk_bf16(p0, p1);
        pk.y = cvt_pk_bf16(p2, p3);
        *(uint2*)&sc[ql * 72 + cg * 16 + lq * 4] = pk;   // overwrite own reads
    }
    l_run += (ltc[0] + ltc[1]) + (ltc[2] + ltc[3]);
    // PV(t) deferred to iter t+1 (or epilogue for t=thi-1)
}

__global__ __launch_bounds__(512, 4)
void attn_mfma(const u16* __restrict__ qu, const u16* __restrict__ qv,
               const u16* __restrict__ kb, const u16* __restrict__ vb,
               const u16* __restrict__ kr, const u64* __restrict__ mbq,
               u16* __restrict__ pO, float* __restrict__ pm,
               float* __restrict__ pl)
{
    __shared__ __align__(16) u16  kt[64 * 64];          //  8192 B (single)
    __shared__ __align__(16) u16  vtbuf[3 * 64 * 64];   // 24576 B (3-slot V^T)
    __shared__ __align__(16) u16  bandc[192 * 64];      // 24576 B (circular)
    __shared__ __align__(16) u16  sc[128 * 72];         // 18432 B (BD, then P)
    __shared__ __align__(16) float r128s[64];
    __shared__ __align__(16) float qv128f[64];
    // total ~76.5 KB -> exactly 2 blocks/CU (16 waves); grid 1536 = 3 rounds

    const int tid = threadIdx.x;
    const int w = tid >> 6, lane = tid & 63;
    const int l15 = lane & 15, lq = lane >> 4;

    // decode: same-bh blocks share an XCD (id%8); 4 K-quarters per unit
    const int id = blockIdx.x;            // 0..1535
    const int xcd = id & 7, slot = id >> 3;       // slot 0..191
    const int group = slot >> 6;                  // 0..2
    const int within = slot & 63;
    const int i0idx = within >> 2, quarter = within & 3;
    const int bh = group * 8 + xcd;               // 0..23
    const int b = bh / H_, h = bh % H_;
    const int i0 = i0idx * 128;
    const int tlo = quarter * 10, thi = tlo + 10;

    const size_t bhs = (size_t)bh;
    const u16* qub = qu + bhs * S_ * 64;
    const u16* qvb = qv + bhs * S_ * 64;
    const u16* kbb = kb + bhs * K_ * 64;
    const u16* vbb = vb + bhs * 64 * K_;     // V^T: [D][K]
    const u16* krb = kr + (size_t)h * K_ * 64;
    const u64* mrow64 = mbq + ((size_t)b * S_ + i0) * 32;

    bf16x8 quA[2], qvA[2];
    {
        const size_t qr = (size_t)(i0 + w * 16 + l15) * 64 + lq * 8;
        quA[0] = *(const bf16x8*)(qub + qr);
        quA[1] = *(const bf16x8*)(qub + qr + 32);
        qvA[0] = *(const bf16x8*)(qvb + qr);
        qvA[1] = *(const bf16x8*)(qvb + qr + 32);
    }
    if (tid < 64) {
        int qr = i0 + 128; if (qr > S_ - 1) qr = S_ - 1;  // clamp row never consumed
        qv128f[tid] = bf2f(qvb[(size_t)qr * 64 + tid]);
    }

    // --- prologue: gll kt(tlo), V(tlo), band g in [64*tlo, 64*tlo+192) ---
    {
        const int j0p = tlo * 64;
        u16* vtP0 = vtbuf + (tlo % 3) * 4096;
        {
            const int key = w * 8 + (lane >> 3);
            const int chunk = (lane & 7) ^ (key & 7);
            gll16(kbb + (size_t)(j0p + key) * 64 + chunk * 8, kt + w * 512);
        }
        {
            const int d = w * 8 + (lane >> 3);
            const int c = (lane & 7) ^ (d & 7);
            gll16(vbb + (size_t)d * K_ + j0p + c * 8, vtP0 + w * 512);
        }
        const int base_p = (tlo % 3) * 64;
        #pragma unroll
        for (int q = 0; q < 3; ++q) {
            const int inst = q * 8 + w;                  // 0..23
            const int j = inst * 8 + (lane >> 3);        // 0..191
            const int g = j0p + j;
            const int diff = g - i0 - 127;
            const int rrow = (diff <= 512) ? (diff + 2047)
                           : ((diff == 513) ? 0 : (diff - 514));
            int pblk = base_p + inst * 8; if (pblk >= 192) pblk -= 192;
            const int chunk = (lane & 7) ^ ((lane >> 3) & 7);
            gll16(krb + (size_t)rrow * 64 + chunk * 8, bandc + pblk * 64);
        }
    }

    float m_run = -3.0e38f, l_run = 0.f;
    f32x4 oacc[4];
    #pragma unroll
    for (int cg = 0; cg < 4; ++cg) oacc[cg] = (f32x4){0.f, 0.f, 0.f, 0.f};

    int t1 = 2 * i0idx + 8;  if (t1 < tlo) t1 = tlo; if (t1 > thi) t1 = thi;
    int t2 = 2 * i0idx + 11; if (t2 < tlo) t2 = tlo; if (t2 > thi) t2 = thi;

    for (int t = tlo; t < t1; ++t)
        attn_tile_step<0>(t, i0, tid, tlo, thi, kbb, vbb, krb, mrow64, quA, qvA,
                          kt, bandc, vtbuf, sc, r128s, qv128f, oacc, m_run, l_run);
    for (int t = t1; t < t2; ++t)
        attn_tile_step<2>(t, i0, tid, tlo, thi, kbb, vbb, krb, mrow64, quA, qvA,
                          kt, bandc, vtbuf, sc, r128s, qv128f, oacc, m_run, l_run);
    for (int t = t2; t < thi; ++t)
        attn_tile_step<1>(t, i0, tid, tlo, thi, kbb, vbb, krb, mrow64, quA, qvA,
                          kt, bandc, vtbuf, sc, r128s, qv128f, oacc, m_run, l_run);

    // --- epilogue: PV(thi-1) ---
    {
        u16* vtP = vtbuf + ((thi - 1) % 3) * 4096;
        const int ql = w * 16 + l15;
        __builtin_amdgcn_s_setprio(1);
        #pragma unroll
        for (int kh = 0; kh < 2; ++kh) {
            const int key0 = lq * 8 + kh * 32;
            const bf16x8 pA = *(const bf16x8*)&sc[ql * 72 + kh * 32 + lq * 8];
            #pragma unroll
            for (int cg = 0; cg < 4; ++cg) {
                const int d = cg * 16 + l15;
                const bf16x8 vB = *(const bf16x8*)&vtP[d * 64 + (key0 ^ ((d & 7) << 3))];
                oacc[cg] = MFMA16(pA, vB, oacc[cg]);
            }
        }
        __builtin_amdgcn_s_setprio(0);
    }

    // --- final l reduction + partial store ---
    l_run += __shfl_xor(l_run, 16, 64);
    l_run += __shfl_xor(l_run, 32, 64);

    const int unit = bh * 16 + i0idx;
    const size_t uid = (size_t)(unit * 4 + quarter);
    #pragma unroll
    for (int cg = 0; cg < 4; ++cg)
        #pragma unroll
        for (int r = 0; r < 4; ++r) {
            const int row = w * 16 + lq * 4 + r;
            pO[uid * 8192 + row * 64 + cg * 16 + l15] = f2bf(oacc[cg][r]);
        }
    if (lq == 0) {
        const int ql = w * 16 + l15;
        pm[uid * 128 + ql] = m_run;
        pl[uid * 128 + ql] = l_run;
    }
}

// ---------------------------------------------------------------------------
extern "C" void kernel_launch(void* const* d_in, const int* in_sizes, int n_in,
                              void* d_out, int out_size, void* d_ws, size_t ws_size,
                              hipStream_t stream)
{
    const float* x     = (const float*)d_in[0];
    const float* mem   = (const float*)d_in[1];
    const float* rpe   = (const float*)d_in[2];
    const int*   amask = (const int*)  d_in[3];
    const float* Wq_w  = (const float*)d_in[5];
    const float* Wq_b  = (const float*)d_in[6];
    const float* Wke_w = (const float*)d_in[7];
    const float* Wke_b = (const float*)d_in[8];
    const float* Wv_w  = (const float*)d_in[9];
    const float* Wv_b  = (const float*)d_in[10];
    const float* Wkr_w = (const float*)d_in[11];
    const float* Wkr_b = (const float*)d_in[12];
    const float* u     = (const float*)d_in[13];
    const float* v     = (const float*)d_in[14];
    const float* Wo_w  = (const float*)d_in[15];
    const float* Wo_b  = (const float*)d_in[16];
    float* out = (float*)d_out;

    // workspace (u16 units); pO aliases the cast region (dead after gemm_fused)
    u16* quB  = (u16*)d_ws;                 // 3,145,728
    u16* qvB  = quB + 3145728;              // 3,145,728
    u16* kbB  = qvB + 3145728;              // 3,932,160
    u16* vbB  = kbB + 3932160;              // 3,932,160 (V^T: [B][H][D][K])
    u16* krB  = vbB + 3932160;              // 1,966,080
    u64* mbB  = (u64*)(krB + 1966080);      // 131,072 u64
    u16* WoB  = (u16*)(mbB + 131072);       // 589,824 (kept live for oproj)
    u16* castB = WoB + 589824;
    u16* kvinB = castB;                     // 3,932,160 (mem rows then x rows)
    u16* rpeB  = kvinB + 3932160;           // 1,966,080
    u16* WqB   = rpeB + 1966080;            // 589,824
    u16* WkeB  = WqB + 589824;
    u16* WvB   = WkeB + 589824;
    u16* WkrB  = WvB + 589824;
    u16* pOB   = castB;                     // ALIAS: 12,582,912 (1536*8192)
    float* pmB = (float*)(pOB + 12582912);  // 196,608 f32
    float* plB = pmB + 196608;              // 196,608 f32

    Cast8 c;
    c.src[0] = mem;   c.dst[0] = kvinB;          c.n4[0] = 786432 / 4;
    c.src[1] = x;     c.dst[1] = kvinB + 786432; c.n4[1] = 3145728 / 4;
    c.src[2] = rpe;   c.dst[2] = rpeB;           c.n4[2] = 1966080 / 4;
    c.src[3] = Wq_w;  c.dst[3] = WqB;            c.n4[3] = 589824 / 4;
    c.src[4] = Wke_w; c.dst[4] = WkeB;           c.n4[4] = 589824 / 4;
    c.src[5] = Wv_w;  c.dst[5] = WvB;            c.n4[5] = 589824 / 4;
    c.src[6] = Wkr_w; c.dst[6] = WkrB;           c.n4[6] = 589824 / 4;
    c.src[7] = Wo_w;  c.dst[7] = WoB;            c.n4[7] = 589824 / 4;
    castk<<<dim3(3072, 9), 256, 0, stream>>>(c, amask, mbB);

    GFused g;
    g.W[0] = WqB;  g.A[0] = kvinB + 786432; g.bias[0] = Wq_b;
    g.W[1] = WkeB; g.A[1] = kvinB;          g.bias[1] = Wke_b;
    g.W[2] = WvB;  g.A[2] = kvinB;          g.bias[2] = Wv_b;
    g.W[3] = WkrB; g.A[3] = rpeB;           g.bias[3] = Wkr_b;
    g.uvec = u; g.vvec = v;
    g.out0[0] = quB; g.out0[1] = kbB; g.out0[2] = vbB; g.out0[3] = krB;
    g.out1 = qvB;
    g.ny[0] = 32; g.ny[1] = 40; g.ny[2] = 40; g.ny[3] = 20;
    gemm_fused<<<dim3(6, 40, 4), 256, 0, stream>>>(g);

    attn_mfma<<<1536, 512, 0, stream>>>(
        quB, qvB, kbB, vbB, krB, mbB, pOB, pmB, plB);

    gemm_oproj<<<dim3(6, 32), 256, 0, stream>>>(
        WoB, pOB, pmB, plB, Wo_b, out);
}

// Round 16
// 247.777 us; speedup vs baseline: 1.2971x; 1.2971x over previous
//
#include <hip/hip_runtime.h>
#include <math.h>

#define S_  2048
#define B_  2
#define M_  512
#define H_  12
#define D_  64
#define DM_ 768
#define K_  2560

typedef short bf16x8 __attribute__((ext_vector_type(8)));
typedef float f32x4  __attribute__((ext_vector_type(4)));
typedef unsigned short u16;
typedef unsigned short u16x4 __attribute__((ext_vector_type(4)));
typedef unsigned short u16x8 __attribute__((ext_vector_type(8)));
typedef unsigned long long u64;

// score prescale: 0.125 * log2(e)  (softmax done in exp2 domain)
#define CSC 0.18033688011112042f

static __device__ __forceinline__ u16 f2bf(float f) {
    unsigned u = __float_as_uint(f);
    u += 0x7fffu + ((u >> 16) & 1u);
    return (u16)(u >> 16);
}
static __device__ __forceinline__ u16 f2bf_fast(float f) {   // round-half-up, 2 ops
    return (u16)((__float_as_uint(f) + 0x8000u) >> 16);
}
static __device__ __forceinline__ float bf2f(u16 h) {
    return __uint_as_float(((unsigned)h) << 16);
}
static __device__ __forceinline__ float exp2_fast(float x) {
    float r;
    asm("v_exp_f32 %0, %1" : "=v"(r) : "v"(x));
    return r;
}
static __device__ __forceinline__ unsigned cvt_pk_bf16(float lo, float hi) {
    unsigned r;
    asm("v_cvt_pk_bf16_f32 %0, %1, %2" : "=v"(r) : "v"(lo), "v"(hi));
    return r;
}
static __device__ __forceinline__ void gll16(const u16* g, u16* l) {
    __builtin_amdgcn_global_load_lds(
        (const __attribute__((address_space(1))) unsigned int*)g,
        (__attribute__((address_space(3))) unsigned int*)l, 16, 0, 0);
}
// LDS drain + barrier WITHOUT vmcnt drain (keeps prefetch loads in flight)
static __device__ __forceinline__ void lgkm_barrier() {
    asm volatile("s_waitcnt lgkmcnt(0)" ::: "memory");
    __builtin_amdgcn_s_barrier();
}
#define MFMA16(a,b,c) __builtin_amdgcn_mfma_f32_16x16x32_bf16((a),(b),(c),0,0,0)

// ---------------------------------------------------------------------------
// cast fp32 -> bf16, 8 segments + mask bitpack (z=8) in one launch
// ---------------------------------------------------------------------------
struct Cast8 {
    const float* src[8];
    u16*         dst[8];
    int          n4[8];
};
__global__ __launch_bounds__(256)
void castk(Cast8 c, const int* __restrict__ am, u64* __restrict__ mb)
{
    const int seg = blockIdx.y;
    if (seg == 8) {   // mask bitpack, grid-stride (wave-aligned: N,stride %64==0)
        const size_t N = (size_t)B_ * S_ * S_;
        for (size_t idx = (size_t)blockIdx.x * 256 + threadIdx.x; idx < N;
             idx += (size_t)3072 * 256) {
            const int v = am[idx];
            const u64 bal = __ballot(v != 0);
            if ((threadIdx.x & 63) == 0) mb[idx >> 6] = bal;
        }
        return;
    }
    const int i = blockIdx.x * 256 + threadIdx.x;
    if (i >= c.n4[seg]) return;
    const float4 v = *(const float4*)(c.src[seg] + (size_t)i * 4);
    u16x4 o;
    o[0] = f2bf(v.x); o[1] = f2bf(v.y); o[2] = f2bf(v.z); o[3] = f2bf(v.w);
    *(u16x4*)(c.dst[seg] + (size_t)i * 4) = o;
}

// ---------------------------------------------------------------------------
// FUSED bf16 MFMA projection GEMMs — one launch, mode = blockIdx.z.
// BK=64 staging (12 K-steps, half the barriers of BK=32; 32 MFMA/step/wave).
//   z=0: Q (dual out qu/qv prescaled by CSC -> [B][H][S][D]), ny=32
//   z=1: K -> [B][H][K][D], ny=40
//   z=2: V^T -> [B][H][D][K], ny=40
//   z=3: R -> [H][K][D], ny=20
// ---------------------------------------------------------------------------
struct GFused {
    const u16*   W[4];
    const u16*   A[4];
    const float* bias[4];
    const float* uvec;
    const float* vvec;
    u16*         out0[4];
    u16*         out1;       // qv (mode 0 only)
    int          ny[4];
};
__global__ __launch_bounds__(256)
void gemm_fused(GFused g)
{
    const int mode = blockIdx.z;
    if ((int)blockIdx.y >= g.ny[mode]) return;

    __shared__ __align__(16) u16 Wt[128 * 64];   // 16 KB
    __shared__ __align__(16) u16 At[128 * 64];   // 16 KB

    const int tid = threadIdx.x;
    const int w = tid >> 6, lane = tid & 63;
    const int l15 = lane & 15, lq = lane >> 4;
    const int wm = w >> 1, wn = w & 1;
    const int c0 = blockIdx.x * 128, r0 = blockIdx.y * 128;

    const u16* __restrict__ Wb = g.W[mode];
    const u16* __restrict__ Ab = g.A[mode];
    const float* __restrict__ bias = g.bias[mode];

    f32x4 acc[4][4];
    #pragma unroll
    for (int mi = 0; mi < 4; ++mi)
        #pragma unroll
        for (int ni = 0; ni < 4; ++ni) acc[mi][ni] = (f32x4){0.f, 0.f, 0.f, 0.f};

    for (int k0 = 0; k0 < DM_; k0 += 64) {
        __syncthreads();
        #pragma unroll
        for (int q = 0; q < 4; ++q) {
            const int inst = w * 4 + q;              // 16 wave-insts cover 1024 slots
            const int sl = inst * 64 + lane;         // 16B slot
            const int row = sl >> 3, cp = sl & 7, ch = cp ^ (row & 7);
            gll16(Wb + (size_t)(c0 + row) * DM_ + k0 + ch * 8, Wt + inst * 512);
            gll16(Ab + (size_t)(r0 + row) * DM_ + k0 + ch * 8, At + inst * 512);
        }
        __syncthreads();
        #pragma unroll
        for (int h2 = 0; h2 < 2; ++h2) {
            const int s8 = lq + h2 * 4;              // k-slot 0..7
            bf16x8 wf[4], af[4];
            #pragma unroll
            for (int mi = 0; mi < 4; ++mi) {
                const int row = wm * 64 + mi * 16 + l15;
                wf[mi] = *(const bf16x8*)&Wt[row * 64 + (s8 ^ (row & 7)) * 8];
            }
            #pragma unroll
            for (int ni = 0; ni < 4; ++ni) {
                const int row = wn * 64 + ni * 16 + l15;
                af[ni] = *(const bf16x8*)&At[row * 64 + (s8 ^ (row & 7)) * 8];
            }
            #pragma unroll
            for (int mi = 0; mi < 4; ++mi)
                #pragma unroll
                for (int ni = 0; ni < 4; ++ni)
                    acc[mi][ni] = MFMA16(wf[mi], af[ni], acc[mi][ni]);
        }
    }

    if (mode == 0) {
        #pragma unroll
        for (int mi = 0; mi < 4; ++mi) {
            const int cb = c0 + wm * 64 + mi * 16 + lq * 4;
            const float4 bb = *(const float4*)(bias + cb);
            const float4 uu = *(const float4*)(g.uvec + cb);
            const float4 vv = *(const float4*)(g.vvec + cb);
            const int qh = cb >> 6, qd = cb & 63;
            #pragma unroll
            for (int ni = 0; ni < 4; ++ni) {
                const int r = r0 + wn * 64 + ni * 16 + l15;
                const f32x4 a = acc[mi][ni];
                const float v0 = a[0] + bb.x, v1 = a[1] + bb.y;
                const float v2 = a[2] + bb.z, v3 = a[3] + bb.w;
                const int s = r >> 1, b = r & 1;
                const size_t off = ((size_t)(b * H_ + qh) * S_ + s) * D_ + qd;
                u16x4 o1, o2;
                o1[0] = f2bf((v0 + uu.x) * CSC); o1[1] = f2bf((v1 + uu.y) * CSC);
                o1[2] = f2bf((v2 + uu.z) * CSC); o1[3] = f2bf((v3 + uu.w) * CSC);
                o2[0] = f2bf((v0 + vv.x) * CSC); o2[1] = f2bf((v1 + vv.y) * CSC);
                o2[2] = f2bf((v2 + vv.z) * CSC); o2[3] = f2bf((v3 + vv.w) * CSC);
                *(u16x4*)(g.out0[0] + off) = o1;
                *(u16x4*)(g.out1 + off) = o2;
            }
        }
    } else if (mode == 1) {
        #pragma unroll
        for (int mi = 0; mi < 4; ++mi) {
            const int cb = c0 + wm * 64 + mi * 16 + lq * 4;
            const float4 bb = *(const float4*)(bias + cb);
            const int qh = cb >> 6, qd = cb & 63;
            #pragma unroll
            for (int ni = 0; ni < 4; ++ni) {
                const int r = r0 + wn * 64 + ni * 16 + l15;
                const f32x4 a = acc[mi][ni];
                int j, b;
                if (r < M_ * B_) { j = r >> 1; b = r & 1; }
                else { const int rr = r - M_ * B_; j = M_ + (rr >> 1); b = rr & 1; }
                const size_t off = ((size_t)(b * H_ + qh) * K_ + j) * D_ + qd;
                u16x4 o1;
                o1[0] = f2bf(a[0] + bb.x); o1[1] = f2bf(a[1] + bb.y);
                o1[2] = f2bf(a[2] + bb.z); o1[3] = f2bf(a[3] + bb.w);
                *(u16x4*)(g.out0[1] + off) = o1;
            }
        }
    } else if (mode == 2) {
        #pragma unroll
        for (int mi = 0; mi < 4; ++mi) {
            const int cb = c0 + wm * 64 + mi * 16 + lq * 4;
            const float4 bb = *(const float4*)(bias + cb);
            const int qh = cb >> 6, qd = cb & 63;
            #pragma unroll
            for (int ni = 0; ni < 4; ++ni) {
                const int r = r0 + wn * 64 + ni * 16 + l15;
                const f32x4 a = acc[mi][ni];
                int j, b;
                if (r < M_ * B_) { j = r >> 1; b = r & 1; }
                else { const int rr = r - M_ * B_; j = M_ + (rr >> 1); b = rr & 1; }
                const size_t rowb = ((size_t)(b * H_ + qh) * 64 + qd);
                u16* o = g.out0[2];
                o[(rowb + 0) * K_ + j] = f2bf(a[0] + bb.x);
                o[(rowb + 1) * K_ + j] = f2bf(a[1] + bb.y);
                o[(rowb + 2) * K_ + j] = f2bf(a[2] + bb.z);
                o[(rowb + 3) * K_ + j] = f2bf(a[3] + bb.w);
            }
        }
    } else {
        #pragma unroll
        for (int mi = 0; mi < 4; ++mi) {
            const int cb = c0 + wm * 64 + mi * 16 + lq * 4;
            const float4 bb = *(const float4*)(bias + cb);
            const int qh = cb >> 6, qd = cb & 63;
            #pragma unroll
            for (int ni = 0; ni < 4; ++ni) {
                const int r = r0 + wn * 64 + ni * 16 + l15;
                const f32x4 a = acc[mi][ni];
                const size_t off = ((size_t)qh * K_ + r) * D_ + qd;
                u16x4 o1;
                o1[0] = f2bf(a[0] + bb.x); o1[1] = f2bf(a[1] + bb.y);
                o1[2] = f2bf(a[2] + bb.z); o1[3] = f2bf(a[3] + bb.w);
                *(u16x4*)(g.out0[3] + off) = o1;
            }
        }
    }
}

// ---------------------------------------------------------------------------
// O-projection GEMM with FUSED split-K combine (reg-staged)
// ---------------------------------------------------------------------------
__global__ __launch_bounds__(256)
void gemm_oproj(const u16* __restrict__ Wb, const u16* __restrict__ pO,
                const float* __restrict__ pm, const float* __restrict__ pl,
                const float* __restrict__ bias, float* __restrict__ out)
{
    __shared__ __align__(16) u16 Wt[128 * 32];
    __shared__ __align__(16) u16 At[128 * 32];

    const int tid = threadIdx.x;
    const int w = tid >> 6, lane = tid & 63;
    const int l15 = lane & 15, lq = lane >> 4;
    const int wm = w >> 1, wn = w & 1;
    const int c0 = blockIdx.x * 128, r0 = blockIdx.y * 128;

    int rowq[2], cpq[2];
    #pragma unroll
    for (int q = 0; q < 2; ++q) {
        const int sl = (w * 2 + q) * 64 + lane;
        rowq[q] = sl >> 2; cpq[q] = sl & 3;
    }

    bf16x8 wreg[2], p0r[2], p1r[2];
    float  m0r[2], m1r[2], l0r[2], l1r[2];

    auto LOADSTAGE = [&](int k0) {
        #pragma unroll
        for (int q = 0; q < 2; ++q) {
            const int row = rowq[q], cp = cpq[q];
            const int c8 = k0 + cp * 8;
            wreg[q] = *(const bf16x8*)(Wb + (size_t)(c0 + row) * DM_ + c8);
            const int tr = r0 + row;
            const int b = tr >> 11, s = tr & 2047;
            const int h = c8 >> 6, d0 = c8 & 63;
            const int unit = (b * H_ + h) * 32 + (s >> 6);
            const int rt = s & 63;
            const size_t u2 = (size_t)unit * 2;
            m0r[q] = pm[u2 * 64 + rt];  m1r[q] = pm[(u2 + 1) * 64 + rt];
            l0r[q] = pl[u2 * 64 + rt];  l1r[q] = pl[(u2 + 1) * 64 + rt];
            p0r[q] = *(const bf16x8*)(pO + u2 * 4096 + rt * 64 + d0);
            p1r[q] = *(const bf16x8*)(pO + (u2 + 1) * 4096 + rt * 64 + d0);
        }
    };
    auto WRITESTAGE = [&]() {
        #pragma unroll
        for (int q = 0; q < 2; ++q) {
            const int row = rowq[q], cp = cpq[q];
            const int j8 = (cp ^ (row & 3)) * 8;
            *(bf16x8*)&Wt[row * 32 + j8] = wreg[q];
            const float M = fmaxf(m0r[q], m1r[q]);
            const float w0 = exp2_fast(m0r[q] - M);
            const float w1 = exp2_fast(m1r[q] - M);
            const float inv = 1.f / (w0 * l0r[q] + w1 * l1r[q]);
            const float a0 = w0 * inv, a1 = w1 * inv;
            u16x8 o;
            #pragma unroll
            for (int e = 0; e < 8; ++e)
                o[e] = f2bf(a0 * bf2f((u16)p0r[q][e]) + a1 * bf2f((u16)p1r[q][e]));
            *(u16x8*)&At[row * 32 + j8] = o;
        }
    };

    f32x4 acc[4][4];
    #pragma unroll
    for (int mi = 0; mi < 4; ++mi)
        #pragma unroll
        for (int ni = 0; ni < 4; ++ni) acc[mi][ni] = (f32x4){0.f, 0.f, 0.f, 0.f};

    LOADSTAGE(0);
    for (int k0 = 0; k0 < DM_; k0 += 32) {
        __syncthreads();
        WRITESTAGE();
        if (k0 + 32 < DM_) LOADSTAGE(k0 + 32);
        lgkm_barrier();
        bf16x8 wf[4], af[4];
        #pragma unroll
        for (int mi = 0; mi < 4; ++mi) {
            const int row = wm * 64 + mi * 16 + l15;
            wf[mi] = *(const bf16x8*)&Wt[row * 32 + (lq ^ (row & 3)) * 8];
        }
        #pragma unroll
        for (int ni = 0; ni < 4; ++ni) {
            const int row = wn * 64 + ni * 16 + l15;
            af[ni] = *(const bf16x8*)&At[row * 32 + (lq ^ (row & 3)) * 8];
        }
        __builtin_amdgcn_s_setprio(1);
        #pragma unroll
        for (int mi = 0; mi < 4; ++mi)
            #pragma unroll
            for (int ni = 0; ni < 4; ++ni)
                acc[mi][ni] = MFMA16(wf[mi], af[ni], acc[mi][ni]);
        __builtin_amdgcn_s_setprio(0);
    }

    #pragma unroll
    for (int mi = 0; mi < 4; ++mi) {
        const int cb = c0 + wm * 64 + mi * 16 + lq * 4;
        const float4 bb = *(const float4*)(bias + cb);
        #pragma unroll
        for (int ni = 0; ni < 4; ++ni) {
            const int r = r0 + wn * 64 + ni * 16 + l15;
            const f32x4 a = acc[mi][ni];
            float4 val;
            val.x = a[0] + bb.x; val.y = a[1] + bb.y;
            val.z = a[2] + bb.z; val.w = a[3] + bb.w;
            *(float4*)(out + (size_t)r * DM_ + cb) = val;
        }
    }
}

// ---------------------------------------------------------------------------
// bf16 MFMA flash attention, split-K, swapped-QK^T, log2-domain softmax,
// deferred max, tree reductions + cvt_pk P stores. (proven best, R12/R14)
// ---------------------------------------------------------------------------
template<int MODE>
static __device__ __forceinline__ void attn_tile_step(
    const int t, const int i0, const int tid, const int tlo, const int thi,
    const u16* __restrict__ kbb, const u16* __restrict__ vbb,
    const u16* __restrict__ krb, const u64* __restrict__ mrow64,
    const bf16x8 (&quA)[2], const bf16x8 (&qvA)[2],
    u16* ktbuf, u16* bandc, u16* vtbuf, u16* sc, float* r64s,
    const float* qv64f,
    f32x4 (&oacc)[4], float& m_run, float& l_run)
{
    const int w = tid >> 6, lane = tid & 63;
    const int l15 = lane & 15, lq = lane >> 4;
    const int ql = w * 16 + l15;               // this lane's softmax row
    const int j0 = t * 64;
    const int base = (t % 3) * 64;             // circular band window base
    const int cgo = 3 - w;                     // BD cg offset for this wave
    u16* kt = ktbuf + (t & 1) * 4096;
    u16* vtP = vtbuf + ((t + 2) % 3) * 4096;   // V(t-1) slot
    const bool last = (t == thi - 1);

    __syncthreads();   // publish kt/band/vt(t); drains gll

    // --- prefetch t+1 ---
    if (!last) {
        const int j0n = j0 + 64;
        u16* ktN = ktbuf + ((t + 1) & 1) * 4096;
        u16* vtN = vtbuf + ((t + 1) % 3) * 4096;
        #pragma unroll
        for (int q = 0; q < 2; ++q) {
            const int inst = w * 2 + q;
            const int key = inst * 8 + (lane >> 3);
            const int chunk = (lane & 7) ^ (key & 7);
            gll16(kbb + (size_t)(j0n + key) * 64 + chunk * 8, ktN + inst * 512);
        }
        #pragma unroll
        for (int q = 0; q < 2; ++q) {
            const int inst = w * 2 + q;
            const int d = inst * 8 + (lane >> 3);
            const int c = (lane & 7) ^ (d & 7);
            gll16(vbb + (size_t)d * K_ + j0n + c * 8, vtN + inst * 512);
        }
        const int pf = (base + 128) % 192;
        #pragma unroll
        for (int q = 0; q < 2; ++q) {
            const int inst = w * 2 + q;
            const int rl = inst * 8 + (lane >> 3);
            const int prow = pf + rl;
            const int diff = (j0 - i0 + 65) + rl;
            const int rrow = (diff <= 512) ? (diff + 2047)
                           : ((diff == 513) ? 0 : (diff - 514));
            const int chunk = (lane & 7) ^ (prow & 7);
            gll16(krb + (size_t)rrow * 64 + chunk * 8, bandc + (pf + inst * 8) * 64);
        }
    }

    // --- mask word for this lane's row (1 load) ---
    const u64 mw = (j0 >= M_) ? mrow64[(size_t)ql * 32 + ((j0 - M_) >> 6)] : ~0ull;

    // --- MFMA cluster: AC^T(t) [swapped], BD(t) [pruned], PV(t-1) ---
    f32x4 ac[4];
    #pragma unroll
    for (int cg = 0; cg < 4; ++cg) ac[cg] = (f32x4){0.f, 0.f, 0.f, 0.f};
    f32x4 bd[5];
    #pragma unroll
    for (int cgi = 0; cgi < 5; ++cgi) bd[cgi] = (f32x4){0.f, 0.f, 0.f, 0.f};
    __builtin_amdgcn_s_setprio(1);
    #pragma unroll
    for (int h2 = 0; h2 < 2; ++h2) {
        const int d0 = lq * 8 + h2 * 32;
        #pragma unroll
        for (int cg = 0; cg < 4; ++cg) {
            const int key = cg * 16 + l15;
            const bf16x8 aK = *(const bf16x8*)&kt[key * 64 + (d0 ^ ((key & 7) << 3))];
            ac[cg] = MFMA16(aK, quA[h2], ac[cg]);   // SWAPPED: C = S^T
        }
        #pragma unroll
        for (int cgi = 0; cgi < 5; ++cgi) {
            const int dd = (cgi + cgo) * 16 + l15;
            int prow = base + dd; if (prow >= 192) prow -= 192;
            const bf16x8 bB = *(const bf16x8*)&bandc[prow * 64 + (d0 ^ ((prow & 7) << 3))];
            bd[cgi] = MFMA16(qvA[h2], bB, bd[cgi]);
        }
    }
    if (t > tlo) {   // PV(t-1): P from sc (A-frag layout), V^T from vtP
        #pragma unroll
        for (int kh = 0; kh < 2; ++kh) {
            const int key0 = lq * 8 + kh * 32;
            const bf16x8 pA = *(const bf16x8*)&sc[ql * 72 + kh * 32 + lq * 8];
            #pragma unroll
            for (int cg = 0; cg < 4; ++cg) {
                const int d = cg * 16 + l15;
                const bf16x8 vB = *(const bf16x8*)&vtP[d * 64 + (key0 ^ ((d & 7) << 3))];
                oacc[cg] = MFMA16(pA, vB, oacc[cg]);
            }
        }
    }
    __builtin_amdgcn_s_setprio(0);

    // --- BD row 64 (wrap source), dd in [0,64) ---
    float rv = 0.f;
    const int rdd = tid >> 1;
    if (MODE != 0 && tid < 128) {
        const int half = tid & 1;
        int prow = base + rdd; if (prow >= 192) prow -= 192;
        #pragma unroll
        for (int c2 = 0; c2 < 4; ++c2) {
            const int d0 = half * 32 + c2 * 8;
            const bf16x8 bv = *(const bf16x8*)&bandc[prow * 64 + (d0 ^ ((prow & 7) << 3))];
            #pragma unroll
            for (int e = 0; e < 8; ++e)
                rv = fmaf(bf2f((u16)bv[e]), qv64f[d0 + e], rv);
        }
        rv += __shfl_xor(rv, 1, 64);
    }

    if (MODE != 0) lgkm_barrier();   // all PV reads of sc done before x-wave writes

    // --- scatter BD -> sc (bf16, stride 72) ---
    const int e0 = l15 + lq * 4 - 15;
    if (MODE == 0) {
        #pragma unroll
        for (int r = 0; r < 4; ++r) {
            const int e = e0 + r;
            u16* rowp = sc + (w * 16 + lq * 4 + r) * 72;
            rowp[e & 63]  = (e < 0) ? f2bf_fast(bd[4][r]) : f2bf_fast(bd[0][r]);
            rowp[16 + e] = f2bf_fast(bd[1][r]);
            rowp[32 + e] = f2bf_fast(bd[2][r]);
            rowp[48 + e] = f2bf_fast(bd[3][r]);
        }
    } else if (MODE == 1) {
        #pragma unroll
        for (int r = 0; r < 4; ++r) {
            const int e1 = e0 + r - 1;
            const int rowm = w * 16 + lq * 4 + r - 1;
            if (rowm >= 0) {
                u16* rowp = sc + rowm * 72;
                rowp[e1 & 63] = (e1 < 0) ? f2bf_fast(bd[4][r]) : f2bf_fast(bd[0][r]);
                rowp[16 + e1] = f2bf_fast(bd[1][r]);
                rowp[32 + e1] = f2bf_fast(bd[2][r]);
                rowp[48 + e1] = f2bf_fast(bd[3][r]);
            }
        }
    } else {   // MODE 2: mixed regimes, predicated (<=2 tiles per block)
        const int diff_base = j0 - i0 - 63;
        #pragma unroll
        for (int cgi = 0; cgi < 5; ++cgi) {
            const int dd = (cgi + cgo) * 16 + l15;
            const int diff_e = diff_base + dd;
            #pragma unroll
            for (int r = 0; r < 4; ++r) {
                const int qlb = w * 16 + lq * 4 + r;
                const int key_n = dd + qlb - 63;
                const u16 val = f2bf_fast(bd[cgi][r]);
                if (diff_e <= 512) {
                    if ((unsigned)key_n < 64u) sc[qlb * 72 + key_n] = val;
                } else if (diff_e >= 514) {
                    const int key_w = key_n - 1;
                    if ((unsigned)key_w < 64u && qlb >= 1) sc[(qlb - 1) * 72 + key_w] = val;
                }
            }
        }
    }
    if (MODE != 0 && tid < 128 && (tid & 1) == 0) r64s[rdd] = rv;

    if (MODE != 0) lgkm_barrier();   // cross-wave sc rows + r64s visible

    // --- softmax (per-lane row ql), exp2 domain, deferred max ---
    float s[4][4];
    #pragma unroll
    for (int cg = 0; cg < 4; ++cg) {
        const u16x4 bq = *(const u16x4*)&sc[ql * 72 + cg * 16 + lq * 4];
        #pragma unroll
        for (int r = 0; r < 4; ++r) {
            const int key = cg * 16 + lq * 4 + r;
            float bdv = bf2f(bq[r]);
            if (MODE == 1) {
                if (ql == 63) bdv = r64s[key];
            } else if (MODE == 2) {
                const int diff = (j0 - i0) + key - ql;
                if (diff == 513) bdv = 0.f;
                else if (diff >= 514 && ql == 63) bdv = r64s[key];
            }
            s[cg][r] = ac[cg][r] + bdv;
        }
    }
    if (mw != ~0ull) {   // mask fast-path: never taken for all-ones mask
        #pragma unroll
        for (int cg = 0; cg < 4; ++cg)
            #pragma unroll
            for (int r = 0; r < 4; ++r) {
                const int key = cg * 16 + lq * 4 + r;
                if (!((mw >> key) & 1ull)) s[cg][r] = -3.0e8f;
            }
    }
    // tree max (depth ~4 instead of 16-deep chain)
    float mcg[4];
    #pragma unroll
    for (int cg = 0; cg < 4; ++cg)
        mcg[cg] = fmaxf(fmaxf(s[cg][0], s[cg][1]), fmaxf(s[cg][2], s[cg][3]));
    float mx = fmaxf(fmaxf(mcg[0], mcg[1]), fmaxf(mcg[2], mcg[3]));
    mx = fmaxf(mx, __shfl_xor(mx, 16, 64));
    mx = fmaxf(mx, __shfl_xor(mx, 32, 64));
    if (!__all(mx <= m_run)) {       // exact deferred-max update (rare)
        const float mn = fmaxf(m_run, mx);
        const float fr = exp2_fast(m_run - mn);
        m_run = mn;
        l_run *= fr;
        #pragma unroll
        for (int r = 0; r < 4; ++r) {
            const float fb = __shfl(fr, lq * 4 + r, 64);
            #pragma unroll
            for (int cg = 0; cg < 4; ++cg) oacc[cg][r] *= fb;
        }
    }
    // P = exp2(s - m); tree-accumulated l; packed bf16 stores via cvt_pk
    float ltc[4];
    #pragma unroll
    for (int cg = 0; cg < 4; ++cg) {
        const float p0 = exp2_fast(s[cg][0] - m_run);
        const float p1 = exp2_fast(s[cg][1] - m_run);
        const float p2 = exp2_fast(s[cg][2] - m_run);
        const float p3 = exp2_fast(s[cg][3] - m_run);
        ltc[cg] = (p0 + p1) + (p2 + p3);
        uint2 pk;
        pk.x = cvt_pk_bf16(p0, p1);
        pk.y = cvt_pk_bf16(p2, p3);
        *(uint2*)&sc[ql * 72 + cg * 16 + lq * 4] = pk;   // overwrite own reads
    }
    l_run += (ltc[0] + ltc[1]) + (ltc[2] + ltc[3]);
    // PV(t) deferred to iter t+1 (or epilogue for t=thi-1)
}

__global__ __launch_bounds__(256, 2)
void attn_mfma(const u16* __restrict__ qu, const u16* __restrict__ qv,
               const u16* __restrict__ kb, const u16* __restrict__ vb,
               const u16* __restrict__ kr, const u64* __restrict__ mbq,
               u16* __restrict__ pO, float* __restrict__ pm,
               float* __restrict__ pl)
{
    __shared__ __align__(16) u16  ktbuf[2 * 64 * 64];   // 16384 B (dbuf)
    __shared__ __align__(16) u16  vtbuf[3 * 64 * 64];   // 24576 B (3-slot V^T)
    __shared__ __align__(16) u16  bandc[192 * 64];      // 24576 B (circular)
    __shared__ __align__(16) u16  sc[64 * 72];          //  9216 B (BD, then P)
    __shared__ __align__(16) float r64s[64];
    __shared__ __align__(16) float qv64f[64];
    // total 75264 B -> exactly 2 blocks/CU; grid 1536 = 3 full rounds

    const int tid = threadIdx.x;
    const int w = tid >> 6, lane = tid & 63;
    const int l15 = lane & 15, lq = lane >> 4;

    // decode: same-bh blocks share an XCD (id%8); 2 K-halves per unit
    const int id = blockIdx.x;            // 0..1535
    const int xcd = id & 7, slot = id >> 3;       // slot 0..191
    const int group = slot >> 6;                  // 0..2
    const int within = slot & 63;
    const int i0idx = within >> 1, half = within & 1;
    const int bh = group * 8 + xcd;               // 0..23
    const int b = bh / H_, h = bh % H_;
    const int i0 = i0idx * 64;
    const int tlo = half * 20, thi = tlo + 20;

    const size_t bhs = (size_t)bh;
    const u16* qub = qu + bhs * S_ * 64;
    const u16* qvb = qv + bhs * S_ * 64;
    const u16* kbb = kb + bhs * K_ * 64;
    const u16* vbb = vb + bhs * 64 * K_;     // V^T: [D][K]
    const u16* krb = kr + (size_t)h * K_ * 64;
    const u64* mrow64 = mbq + ((size_t)b * S_ + i0) * 32;

    bf16x8 quA[2], qvA[2];
    {
        const size_t qr = (size_t)(i0 + w * 16 + l15) * 64 + lq * 8;
        quA[0] = *(const bf16x8*)(qub + qr);
        quA[1] = *(const bf16x8*)(qub + qr + 32);
        qvA[0] = *(const bf16x8*)(qvb + qr);
        qvA[1] = *(const bf16x8*)(qvb + qr + 32);
    }
    if (tid < 64) {
        int qr = i0 + 64; if (qr > S_ - 1) qr = S_ - 1;   // clamp row never consumed
        qv64f[tid] = bf2f(qvb[(size_t)qr * 64 + tid]);
    }

    // --- prologue: gll kt(tlo), band g in [64*tlo, 64*tlo+128), V(tlo) ---
    {
        const int j0p = tlo * 64;
        u16* ktP0 = ktbuf + (tlo & 1) * 4096;
        u16* vtP0 = vtbuf + (tlo % 3) * 4096;
        #pragma unroll
        for (int q = 0; q < 2; ++q) {
            const int inst = w * 2 + q;
            const int key = inst * 8 + (lane >> 3);
            const int chunk = (lane & 7) ^ (key & 7);
            gll16(kbb + (size_t)(j0p + key) * 64 + chunk * 8, ktP0 + inst * 512);
        }
        #pragma unroll
        for (int q = 0; q < 2; ++q) {
            const int inst = w * 2 + q;
            const int d = inst * 8 + (lane >> 3);
            const int c = (lane & 7) ^ (d & 7);
            gll16(vbb + (size_t)d * K_ + j0p + c * 8, vtP0 + inst * 512);
        }
        #pragma unroll
        for (int q = 0; q < 4; ++q) {
            const int inst = w * 4 + q;
            const int j = inst * 8 + (lane >> 3);            // 0..127
            const int g = j0p + j;                           // global band row
            const int diff = g - i0 - 63;
            const int rrow = (diff <= 512) ? (diff + 2047)
                           : ((diff == 513) ? 0 : (diff - 514));
            const int prow = (j0p + inst * 8) % 192;          // phys block base
            const int chunk = (lane & 7) ^ ((prow + (lane >> 3)) & 7);
            gll16(krb + (size_t)rrow * 64 + chunk * 8, bandc + prow * 64);
        }
    }

    float m_run = -3.0e38f, l_run = 0.f;
    f32x4 oacc[4];
    #pragma unroll
    for (int cg = 0; cg < 4; ++cg) oacc[cg] = (f32x4){0.f, 0.f, 0.f, 0.f};

    const int ti = i0 >> 6;
    int t1 = ti + 8;  if (t1 < tlo) t1 = tlo; if (t1 > thi) t1 = thi;
    int t2 = ti + 10; if (t2 < tlo) t2 = tlo; if (t2 > thi) t2 = thi;

    for (int t = tlo; t < t1; ++t)
        attn_tile_step<0>(t, i0, tid, tlo, thi, kbb, vbb, krb, mrow64, quA, qvA,
                          ktbuf, bandc, vtbuf, sc, r64s, qv64f,
                          oacc, m_run, l_run);
    for (int t = t1; t < t2; ++t)
        attn_tile_step<2>(t, i0, tid, tlo, thi, kbb, vbb, krb, mrow64, quA, qvA,
                          ktbuf, bandc, vtbuf, sc, r64s, qv64f,
                          oacc, m_run, l_run);
    for (int t = t2; t < thi; ++t)
        attn_tile_step<1>(t, i0, tid, tlo, thi, kbb, vbb, krb, mrow64, quA, qvA,
                          ktbuf, bandc, vtbuf, sc, r64s, qv64f,
                          oacc, m_run, l_run);

    // --- epilogue: PV(thi-1) ---
    {
        u16* vtP = vtbuf + ((thi - 1) % 3) * 4096;
        const int ql = w * 16 + l15;
        __builtin_amdgcn_s_setprio(1);
        #pragma unroll
        for (int kh = 0; kh < 2; ++kh) {
            const int key0 = lq * 8 + kh * 32;
            const bf16x8 pA = *(const bf16x8*)&sc[ql * 72 + kh * 32 + lq * 8];
            #pragma unroll
            for (int cg = 0; cg < 4; ++cg) {
                const int d = cg * 16 + l15;
                const bf16x8 vB = *(const bf16x8*)&vtP[d * 64 + (key0 ^ ((d & 7) << 3))];
                oacc[cg] = MFMA16(pA, vB, oacc[cg]);
            }
        }
        __builtin_amdgcn_s_setprio(0);
    }

    // --- final l reduction + partial store ---
    l_run += __shfl_xor(l_run, 16, 64);
    l_run += __shfl_xor(l_run, 32, 64);

    const int unit = bh * 32 + i0idx;
    const size_t uid2 = (size_t)(unit * 2 + half);
    #pragma unroll
    for (int cg = 0; cg < 4; ++cg)
        #pragma unroll
        for (int r = 0; r < 4; ++r) {
            const int row = w * 16 + lq * 4 + r;
            pO[uid2 * 4096 + row * 64 + cg * 16 + l15] = f2bf(oacc[cg][r]);
        }
    if (lq == 0) {
        const int ql = w * 16 + l15;
        pm[uid2 * 64 + ql] = m_run;
        pl[uid2 * 64 + ql] = l_run;
    }
}

// ---------------------------------------------------------------------------
extern "C" void kernel_launch(void* const* d_in, const int* in_sizes, int n_in,
                              void* d_out, int out_size, void* d_ws, size_t ws_size,
                              hipStream_t stream)
{
    const float* x     = (const float*)d_in[0];
    const float* mem   = (const float*)d_in[1];
    const float* rpe   = (const float*)d_in[2];
    const int*   amask = (const int*)  d_in[3];
    const float* Wq_w  = (const float*)d_in[5];
    const float* Wq_b  = (const float*)d_in[6];
    const float* Wke_w = (const float*)d_in[7];
    const float* Wke_b = (const float*)d_in[8];
    const float* Wv_w  = (const float*)d_in[9];
    const float* Wv_b  = (const float*)d_in[10];
    const float* Wkr_w = (const float*)d_in[11];
    const float* Wkr_b = (const float*)d_in[12];
    const float* u     = (const float*)d_in[13];
    const float* v     = (const float*)d_in[14];
    const float* Wo_w  = (const float*)d_in[15];
    const float* Wo_b  = (const float*)d_in[16];
    float* out = (float*)d_out;

    u16* quB  = (u16*)d_ws;                 // u16 counts
    u16* qvB  = quB + 3145728;
    u16* kbB  = qvB + 3145728;
    u16* vbB  = kbB + 3932160;              // V^T: [B][H][D][K]
    u16* krB  = vbB + 3932160;
    u64* mbB  = (u64*)(krB + 1966080);      // 131,072 u64
    u16* castB = (u16*)(mbB + 131072);
    u16* kvinB = castB;                     // 3,932,160 (mem rows then x rows)
    u16* rpeB  = kvinB + 3932160;           // 1,966,080
    u16* WqB   = rpeB + 1966080;            // 589,824
    u16* WkeB  = WqB + 589824;
    u16* WvB   = WkeB + 589824;
    u16* WkrB  = WvB + 589824;
    u16* WoB   = WkrB + 589824;             // 589,824
    u16* pOB   = WoB + 589824;              // 6,291,456 u16 (768*2*4096 bf16)
    float* pmB = (float*)(pOB + 6291456);   // 98,304 f32
    float* plB = pmB + 98304;               // 98,304 f32

    Cast8 c;
    c.src[0] = mem;   c.dst[0] = kvinB;          c.n4[0] = 786432 / 4;
    c.src[1] = x;     c.dst[1] = kvinB + 786432; c.n4[1] = 3145728 / 4;
    c.src[2] = rpe;   c.dst[2] = rpeB;           c.n4[2] = 1966080 / 4;
    c.src[3] = Wq_w;  c.dst[3] = WqB;            c.n4[3] = 589824 / 4;
    c.src[4] = Wke_w; c.dst[4] = WkeB;           c.n4[4] = 589824 / 4;
    c.src[5] = Wv_w;  c.dst[5] = WvB;            c.n4[5] = 589824 / 4;
    c.src[6] = Wkr_w; c.dst[6] = WkrB;           c.n4[6] = 589824 / 4;
    c.src[7] = Wo_w;  c.dst[7] = WoB;            c.n4[7] = 589824 / 4;
    castk<<<dim3(3072, 9), 256, 0, stream>>>(c, amask, mbB);

    GFused g;
    g.W[0] = WqB;  g.A[0] = kvinB + 786432; g.bias[0] = Wq_b;
    g.W[1] = WkeB; g.A[1] = kvinB;          g.bias[1] = Wke_b;
    g.W[2] = WvB;  g.A[2] = kvinB;          g.bias[2] = Wv_b;
    g.W[3] = WkrB; g.A[3] = rpeB;           g.bias[3] = Wkr_b;
    g.uvec = u; g.vvec = v;
    g.out0[0] = quB; g.out0[1] = kbB; g.out0[2] = vbB; g.out0[3] = krB;
    g.out1 = qvB;
    g.ny[0] = 32; g.ny[1] = 40; g.ny[2] = 40; g.ny[3] = 20;
    gemm_fused<<<dim3(6, 40, 4), 256, 0, stream>>>(g);

    attn_mfma<<<1536, 256, 0, stream>>>(
        quB, qvB, kbB, vbB, krB, mbB, pOB, pmB, plB);

    gemm_oproj<<<dim3(6, 32), 256, 0, stream>>>(
        WoB, pOB, pmB, plB, Wo_b, out);
}